// Round 7
// baseline (620.691 us; speedup 1.0000x reference)
//
#include <hip/hip_runtime.h>
#include <hip/hip_bf16.h>

// AngularMarginLoss: B=2048, D=256, C=100000
// loss = -mean_b( num_b - log(exp(num_b) + sum_{c!=t_b} exp(30*cos_bc) + 1e-6) )
// num_b = 30*cos(acos(clip(cos_bt)) + 0.2)
//
// Round-14: the number that fits every round: B-traffic/duration ~= 10-12
// TB/s (1.6GB embF re-reads / 132-184us in R8/R10/R12/R13b). The kernel is
// B-BANDWIDTH-bound at the L2/L3 mix rate; nt-hints (R13b) moved nothing.
// Only arithmetic intensity helps: traffic = 100MB*(2048/Nc) + 1MB*(CPAD/Mc).
//  * Mc=128 classes/block (was 64): B-traffic 1.6GB -> 0.8GB, W still read
//    once. Grid 782 x 256thr (4 waves), 64KB LDS A-frags; each 1KB B-frag
//    feeds 64 MFMAs (was 32).
//  * __launch_bounds__(256,2): 2 waves/EU -> 256-VGPR budget -> B ping-pong
//    (128 regs) + acc (64) stay in registers (R12/13's 128-cap squeezed the
//    prefetch out). LDS 64.5KB -> 2 blocks/CU.
//  * Prologue: 2 threads/row, 128 floats in regs, norm = one shfl_xor(ss,1);
//    no ssq array, single barrier. Conflict-free frag writes.
//  * Keep: 32x32x16 MFMA, embF pre-scaled by 30*log2(e) (exp = 1 v_exp2).

static constexpr int Bn = 2048;
static constexpr int Dn = 256;
static constexpr int Cn = 100000;
static constexpr int MC = 128;                      // classes per block
static constexpr int NSLICE = 782;                  // ceil(100000/128)
static constexpr int CPAD   = NSLICE * MC;          // 100096
static constexpr float OOB_COLS = (float)(CPAD - Cn);   // 96 (exp2(0)=1 each)
static constexpr int NT  = Bn / 32;                 // 64 sample tiles (32-wide)
static constexpr int NWV = 4;                       // waves per block
static constexpr int NTW = NT / NWV;                // 16 tiles per wave

#define SCALE_F 30.0f
#define MARGIN_F 0.2f
#define EPS_F 1e-6f
#define L2E_SCALE 43.2808512266689f   /* 30 * log2(e): exp(30*c) = 2^(L2E*c) */

typedef __attribute__((ext_vector_type(8))) short bf16x8;    // 8 bf16 = 4 VGPRs
typedef __attribute__((ext_vector_type(16))) float f32x16;   // 32x32 acc
typedef __attribute__((ext_vector_type(4))) float f32x4v;    // nt-load friendly

__device__ __forceinline__ short f2bf_rne(float x) {
    union { float f; unsigned int u; } v; v.f = x;
    unsigned int r = v.u + 0x7fffu + ((v.u >> 16) & 1u);
    return (short)(r >> 16);
}

// ---- kernel 1: fused prep ----
// blocks [0,256)    : pack emb fp32 -> embF (bf16, 32x32x16 MFMA B-fragment
//                     order), PRE-SCALED by 30*log2(e).
//   chunk (t,ks,lane): embF[((t*16+ks)*64+lane)*8 .. +7] = bf16 of
//   L2E * emb[t*32 + (lane&31)][ks*16 + (lane>>5)*8 + j], j=0..7
// blocks [256,768)  : per-sample target cosine -> numv, etv (exact fp32 path)
__global__ __launch_bounds__(256) void k_prep(const float* __restrict__ W,
                                              const float* __restrict__ emb,
                                              const int* __restrict__ tgt,
                                              short* __restrict__ embF,
                                              float* __restrict__ numv,
                                              float* __restrict__ etv) {
    const int blk = blockIdx.x;
    if (blk < 256) {
        const int t     = blk >> 2;                        // sample tile 0..63
        const int chunk = (blk & 3) * 256 + threadIdx.x;   // [0,1024)
        const int ks    = chunk >> 6;                      // 0..15
        const int lane  = chunk & 63;
        const float* src = emb + (size_t)(t * 32 + (lane & 31)) * Dn
                               + ks * 16 + (lane >> 5) * 8;
        float4 x0 = *(const float4*)(src);
        float4 x1 = *(const float4*)(src + 4);
        bf16x8 o;
        o[0] = f2bf_rne(x0.x * L2E_SCALE); o[1] = f2bf_rne(x0.y * L2E_SCALE);
        o[2] = f2bf_rne(x0.z * L2E_SCALE); o[3] = f2bf_rne(x0.w * L2E_SCALE);
        o[4] = f2bf_rne(x1.x * L2E_SCALE); o[5] = f2bf_rne(x1.y * L2E_SCALE);
        o[6] = f2bf_rne(x1.z * L2E_SCALE); o[7] = f2bf_rne(x1.w * L2E_SCALE);
        *(bf16x8*)(embF + (size_t)((t * 16 + ks) * 64 + lane) * 8) = o;
    } else {
        const int b    = (blk - 256) * 4 + (threadIdx.x >> 6);
        const int lane = threadIdx.x & 63;
        const int t    = tgt[b];
        float4 x = *(const float4*)(W + (size_t)t * Dn + lane * 4);
        float4 e = *(const float4*)(emb + b * Dn + lane * 4);
        float dot = x.x * e.x + x.y * e.y + x.z * e.z + x.w * e.w;
        float ss  = x.x * x.x + x.y * x.y + x.z * x.z + x.w * x.w;
#pragma unroll
        for (int o = 1; o < 64; o <<= 1) {
            dot += __shfl_xor(dot, o);
            ss  += __shfl_xor(ss, o);
        }
        if (lane == 0) {
            float cosv = dot / fmaxf(sqrtf(ss), 1e-12f);
            cosv = fminf(fmaxf(cosv, -1.f), 1.f);
            const float num = SCALE_F * cosf(acosf(cosv) + MARGIN_F);
            numv[b] = num;
            etv[b]  = __expf(SCALE_F * cosv);
        }
    }
}

// ---- kernel 2: main fused GEMM + exp row-sum ----
// Block = one 128-class slice, 4 waves (256 thr). Cooperative one-pass
// W-normalize into 64KB LDS (A-frags, 32x32x16 layout), then each wave owns
// 16 sample-tiles of 32, barrier-free; B ping-pong in regs (256-VGPR budget).
__global__ __launch_bounds__(256, 2) void k_main(const float* __restrict__ W,
                                                 const short* __restrict__ embF,
                                                 float* __restrict__ partial) {
    __shared__ short afrag_sh[4 * 16 * 64 * 8];   // 64 KB: [(ct*16+ks)*64+l']*8
    const int tid  = threadIdx.x;
    const int lane = tid & 63;
    const int wv   = tid >> 6;    // wave id 0..3
    const int sl   = blockIdx.x;
    const int cbase = sl * MC;

    // ---- prologue: 2 threads per class-row: r = tid>>1, kh = tid&1 owns
    // k in [kh*128, +128). 128 floats in regs; row-norm via shfl_xor(ss,1).
    {
        const int r   = tid >> 1;        // row-in-slice 0..127
        const int kh  = tid & 1;
        const int c   = cbase + r;
        float v[128];
        if (c < Cn) {
            const f32x4v* wr = (const f32x4v*)(W + (size_t)c * Dn + kh * 128);
#pragma unroll
            for (int j = 0; j < 32; ++j) {
                f32x4v x = __builtin_nontemporal_load(wr + j);
                v[j * 4 + 0] = x.x; v[j * 4 + 1] = x.y;
                v[j * 4 + 2] = x.z; v[j * 4 + 3] = x.w;
            }
        } else {
#pragma unroll
            for (int j = 0; j < 128; ++j) v[j] = 0.0f;
        }
        float ss = 0.0f;
#pragma unroll
        for (int j = 0; j < 128; ++j) ss += v[j] * v[j];
        ss += __shfl_xor(ss, 1);         // lanes 2i,2i+1 share row r
        const float rn = 1.0f / fmaxf(sqrtf(ss), 1e-12f);
        // A layout (32x32x16): frag (ct,ks), lane l': row=ct*32+(l'&31),
        // k = ks*16 + (l'>>5)*8 + j. This thread: rows ct=r>>5, r31=r&31;
        // k = kh*128 + ksl*16 + h*8 + j -> ks = kh*8+ksl, l' = h*32+r31.
        const int ct  = r >> 5;
        const int r31 = r & 31;
#pragma unroll
        for (int ksl = 0; ksl < 8; ++ksl) {
            const int ks = kh * 8 + ksl;
#pragma unroll
            for (int h = 0; h < 2; ++h) {
                bf16x8 a;
#pragma unroll
                for (int j = 0; j < 8; ++j)
                    a[j] = f2bf_rne(v[ksl * 16 + h * 8 + j] * rn);
                *(bf16x8*)(afrag_sh +
                           (size_t)((ct * 16 + ks) * 64 + h * 32 + r31) * 8) = a;
            }
        }
    }
    __syncthreads();

    float* pout = partial + (size_t)sl * Bn;
    const bf16x8* bsrc = (const bf16x8*)embF;   // chunk-indexed (16B units)
    const int t0 = wv * NTW;                    // this wave's 16 sample tiles

    // B fragments for tile t: chunks t*1024 + ks*64 + lane (coalesced 1KB/inst)
    auto load_b = [&](bf16x8* bf, int t) {
        const bf16x8* p = bsrc + ((size_t)t << 10) + lane;
#pragma unroll
        for (int ks = 0; ks < 16; ++ks) bf[ks] = p[ks * 64];
    };

    auto compute = [&](const bf16x8* bf, int t) {
        f32x16 a0 = {0.f,0.f,0.f,0.f,0.f,0.f,0.f,0.f,0.f,0.f,0.f,0.f,0.f,0.f,0.f,0.f};
        f32x16 a1 = a0, a2 = a0, a3 = a0;
#pragma unroll
        for (int ks = 0; ks < 16; ++ks) {
            const short* ap = afrag_sh + (size_t)(ks * 64 + lane) * 8;
            bf16x8 w0 = *(const bf16x8*)(ap);                // ct=0
            bf16x8 w1 = *(const bf16x8*)(ap + 8192);         // ct=1
            bf16x8 w2 = *(const bf16x8*)(ap + 16384);        // ct=2
            bf16x8 w3 = *(const bf16x8*)(ap + 24576);        // ct=3
            a0 = __builtin_amdgcn_mfma_f32_32x32x16_bf16(w0, bf[ks], a0, 0, 0, 0);
            a1 = __builtin_amdgcn_mfma_f32_32x32x16_bf16(w1, bf[ks], a1, 0, 0, 0);
            a2 = __builtin_amdgcn_mfma_f32_32x32x16_bf16(w2, bf[ks], a2, 0, 0, 0);
            a3 = __builtin_amdgcn_mfma_f32_32x32x16_bf16(w3, bf[ks], a3, 0, 0, 0);
        }
        // D layout (32x32): col=lane&31=sample; 16 regs x 2 lane-halves cover
        // each class-row once. d = 30*log2e*cos -> exp2 directly.
        float s0 = 0.f, s1 = 0.f, s2 = 0.f, s3 = 0.f;
#pragma unroll
        for (int r = 0; r < 16; r += 4) {
            s0 += __builtin_amdgcn_exp2f(a0[r+0]) + __builtin_amdgcn_exp2f(a1[r+0])
                + __builtin_amdgcn_exp2f(a2[r+0]) + __builtin_amdgcn_exp2f(a3[r+0]);
            s1 += __builtin_amdgcn_exp2f(a0[r+1]) + __builtin_amdgcn_exp2f(a1[r+1])
                + __builtin_amdgcn_exp2f(a2[r+1]) + __builtin_amdgcn_exp2f(a3[r+1]);
            s2 += __builtin_amdgcn_exp2f(a0[r+2]) + __builtin_amdgcn_exp2f(a1[r+2])
                + __builtin_amdgcn_exp2f(a2[r+2]) + __builtin_amdgcn_exp2f(a3[r+2]);
            s3 += __builtin_amdgcn_exp2f(a0[r+3]) + __builtin_amdgcn_exp2f(a1[r+3])
                + __builtin_amdgcn_exp2f(a2[r+3]) + __builtin_amdgcn_exp2f(a3[r+3]);
        }
        float s = (s0 + s1) + (s2 + s3);
        s += __shfl_xor(s, 32);                     // merge row-halves
        if (lane < 32)
            __builtin_nontemporal_store(s, pout + t * 32 + lane);  // 128B, nt
    };

    bf16x8 b0[16], b1[16];
    load_b(b0, t0);
    for (int i = 0; i < NTW; i += 2) {
        load_b(b1, t0 + i + 1);                          // prefetch next tile
        compute(b0, t0 + i);
        load_b(b0, (i + 2) < NTW ? (t0 + i + 2) : t0);   // overrun-clamped
        compute(b1, t0 + i + 1);
    }
}

// ---- kernel 3: fused rowsum + loss ----
// 128 blocks x 256 thr; block owns 16 samples; tid = chunk*16 + l.
__global__ __launch_bounds__(256) void k_finish(const float* __restrict__ partial,
                                                const float* __restrict__ numv,
                                                const float* __restrict__ etv,
                                                float* __restrict__ out) {
    __shared__ float red[16];
    const int l     = threadIdx.x & 15;          // sample within block
    const int chunk = threadIdx.x >> 4;          // 0..15
    const int b  = blockIdx.x * 16 + l;

    if (threadIdx.x < 16) red[threadIdx.x] = 0.0f;
    __syncthreads();

    float acc = 0.0f;
    for (int s = chunk; s < NSLICE; s += 16) acc += partial[(size_t)s * Bn + b];
    // wave holds 4 chunks x 16 samples: fold chunks in-wave first
    acc += __shfl_xor(acc, 16);
    acc += __shfl_xor(acc, 32);
    if ((threadIdx.x & 63) < 16) atomicAdd(&red[l], acc);
    __syncthreads();

    if (threadIdx.x < 16) {
        const int bb = blockIdx.x * 16 + threadIdx.x;
        const float num  = numv[bb];
        const float excl = red[threadIdx.x] - OOB_COLS - etv[bb];  // drop pad + target
        float term = num - logf(__expf(num) + excl + EPS_F);
#pragma unroll
        for (int o = 1; o < 16; o <<= 1) term += __shfl_xor(term, o);
        if (threadIdx.x == 0) atomicAdd(out, -term / (float)Bn);
    }
}

extern "C" void kernel_launch(void* const* d_in, const int* in_sizes, int n_in,
                              void* d_out, int out_size, void* d_ws, size_t ws_size,
                              hipStream_t stream) {
    const float* emb = (const float*)d_in[0];   // 2048*256
    const float* W   = (const float*)d_in[1];   // 100000*256
    const int*   tgt = (const int*)d_in[2];     // 2048
    float* out = (float*)d_out;

    char* ws = (char*)d_ws;
    short* embF    = (short*)ws;                             // 1 MB (fragment order)
    float* partial = (float*)(ws + (1 << 20));               // 782*2048*4 = 6.4 MB
    float* numv    = partial + (size_t)NSLICE * Bn;          // 8 KB
    float* etv     = numv + Bn;                              // 8 KB

    hipMemsetAsync(out, 0, sizeof(float), stream);
    k_prep<<<768, 256, 0, stream>>>(W, emb, tgt, embF, numv, etv);
    k_main<<<NSLICE, 256, 0, stream>>>(W, embF, partial);
    k_finish<<<128, 256, 0, stream>>>(partial, numv, etv, out);
}

// Round 8
// 298.978 us; speedup vs baseline: 2.0760x; 2.0760x over previous
//
#include <hip/hip_runtime.h>
#include <hip/hip_bf16.h>

// AngularMarginLoss: B=2048, D=256, C=100000
// loss = -mean_b( num_b - log(exp(num_b) + sum_{c!=t_b} exp(30*cos_bc) + 1e-6) )
// num_b = 30*cos(acos(clip(cos_bt)) + 0.2)
//
// Round-15: back to the proven R10 config (132us k_main, best), ONE change.
// R10 was LDS-issue-bound: 1 ds_read_b128 per MFMA = 25.6MB/CU ~ 125us at
// 85 B/cyc -- the measured 132us. Fix: reuse each A-frag for TWO N-subtiles
// (per-wave tile = 32 samples, two 16-col B sets): per ks, 4 ds_reads feed
// 8 MFMAs -> LDS/CU halves to 12.8MB ~ 63us; MFMA 52us; exp ~35us overlap.
//  * acc[4][2] f32x4 + b0[2][8]/b1[2][8] ping-pong (128 VGPR, all static
//    indices after unroll). __launch_bounds__(256,1): NO 128-reg cap --
//    arg2=2 empirically caps VGPR at 128 (R10/R12/R14), which would sink
//    the ping-pong; arg2=4 caused R11's spill disaster.
//  * k_prep / prologue / embF 16-wide fragment layout / k_finish unchanged
//    from R10 (a 32-tile = two adjacent 16-tiles).
//  * embF pre-scaled by 30*log2(e): exp(30*cos) = one v_exp2_f32.

static constexpr int Bn = 2048;
static constexpr int Dn = 256;
static constexpr int Cn = 100000;
static constexpr int NSLICE = 1564;                 // 64-class slices
static constexpr int CPAD   = NSLICE * 64;          // 100096
static constexpr float OOB_COLS = (float)(CPAD - Cn);   // 96 (exp2(0)=1 each)
static constexpr int NT  = Bn / 32;                 // 64 sample tiles (32-wide)
static constexpr int NWV = 4;                       // waves per block
static constexpr int NTW = NT / NWV;                // 16 tiles per wave

#define SCALE_F 30.0f
#define MARGIN_F 0.2f
#define EPS_F 1e-6f
#define L2E_SCALE 43.2808512266689f   /* 30 * log2(e): exp(30*c) = 2^(L2E*c) */

typedef __attribute__((ext_vector_type(8))) short bf16x8;   // 8 bf16 = 4 VGPRs
typedef __attribute__((ext_vector_type(4))) float f32x4;

__device__ __forceinline__ short f2bf_rne(float x) {
    union { float f; unsigned int u; } v; v.f = x;
    unsigned int r = v.u + 0x7fffu + ((v.u >> 16) & 1u);
    return (short)(r >> 16);
}

// ---- kernel 1: fused prep ----
// blocks [0,256)    : pack emb fp32 -> embF (bf16, 16x16x32 MFMA B-fragment
//                     order, 16-wide tiles), PRE-SCALED by 30*log2(e).
//   chunk (t,ks,lane): embF[((t*8+ks)*64+lane)*8 .. +7] = bf16 of
//   L2E * emb[t*16 + (lane&15)][ks*32 + (lane>>4)*8 + j], j=0..7
// blocks [256,768)  : per-sample target cosine -> numv, etv (exact fp32 path)
__global__ __launch_bounds__(256) void k_prep(const float* __restrict__ W,
                                              const float* __restrict__ emb,
                                              const int* __restrict__ tgt,
                                              short* __restrict__ embF,
                                              float* __restrict__ numv,
                                              float* __restrict__ etv) {
    const int blk = blockIdx.x;
    if (blk < 256) {
        const int t     = blk >> 1;
        const int chunk = (blk & 1) * 256 + threadIdx.x;   // [0,512)
        const int ks    = chunk >> 6;
        const int lane  = chunk & 63;
        const int q     = lane >> 4;
        const int cr    = lane & 15;
        const float* src = emb + (size_t)(t * 16 + cr) * Dn + ks * 32 + q * 8;
        float4 x0 = *(const float4*)(src);
        float4 x1 = *(const float4*)(src + 4);
        bf16x8 o;
        o[0] = f2bf_rne(x0.x * L2E_SCALE); o[1] = f2bf_rne(x0.y * L2E_SCALE);
        o[2] = f2bf_rne(x0.z * L2E_SCALE); o[3] = f2bf_rne(x0.w * L2E_SCALE);
        o[4] = f2bf_rne(x1.x * L2E_SCALE); o[5] = f2bf_rne(x1.y * L2E_SCALE);
        o[6] = f2bf_rne(x1.z * L2E_SCALE); o[7] = f2bf_rne(x1.w * L2E_SCALE);
        *(bf16x8*)(embF + (size_t)((t * 8 + ks) * 64 + lane) * 8) = o;
    } else {
        const int b    = (blk - 256) * 4 + (threadIdx.x >> 6);
        const int lane = threadIdx.x & 63;
        const int t    = tgt[b];
        float4 x = *(const float4*)(W + (size_t)t * Dn + lane * 4);
        float4 e = *(const float4*)(emb + b * Dn + lane * 4);
        float dot = x.x * e.x + x.y * e.y + x.z * e.z + x.w * e.w;
        float ss  = x.x * x.x + x.y * x.y + x.z * x.z + x.w * x.w;
#pragma unroll
        for (int o = 1; o < 64; o <<= 1) {
            dot += __shfl_xor(dot, o);
            ss  += __shfl_xor(ss, o);
        }
        if (lane == 0) {
            float cosv = dot / fmaxf(sqrtf(ss), 1e-12f);
            cosv = fminf(fmaxf(cosv, -1.f), 1.f);
            const float num = SCALE_F * cosf(acosf(cosv) + MARGIN_F);
            numv[b] = num;
            etv[b]  = __expf(SCALE_F * cosv);
        }
    }
}

// ---- kernel 2: main fused GEMM + exp row-sum ----
// Block = one 64-class slice, 4 waves. R10's cooperative W-normalize prologue
// (wave wv = class-tile ct), then each wave owns 16 sample-tiles of 32
// (two 16-col halves sharing every A-frag read), barrier-free.
__global__ __launch_bounds__(256, 1) void k_main(const float* __restrict__ W,
                                                 const short* __restrict__ embF,
                                                 float* __restrict__ partial) {
    __shared__ short afrag_sh[4 * 8 * 64 * 8];   // 32 KB, [(ct*8+ks)*64+lane]*8
    const int tid  = threadIdx.x;
    const int lane = tid & 63;
    const int wv   = tid >> 6;    // wave id 0..3 (= ct in prologue)
    const int q    = lane >> 4;   // quad 0..3
    const int cr   = lane & 15;
    const int sl   = blockIdx.x;
    const int cbase = sl * 64;

    // ---- prologue: wave wv normalizes cols [cbase+wv*16, +16) (R10 verbatim)
    {
        const int c = cbase + wv * 16 + cr;
        const float* wr = W + (size_t)c * Dn;
        float ss = 0.0f;
        if (c < Cn) {
#pragma unroll
            for (int ks = 0; ks < 8; ++ks) {
                float4 x0 = *(const float4*)(wr + ks * 32 + q * 8);
                float4 x1 = *(const float4*)(wr + ks * 32 + q * 8 + 4);
                ss += x0.x * x0.x + x0.y * x0.y + x0.z * x0.z + x0.w * x0.w;
                ss += x1.x * x1.x + x1.y * x1.y + x1.z * x1.z + x1.w * x1.w;
            }
        }
        // lanes {cr, cr+16, cr+32, cr+48} hold 64 distinct elements of row c
        ss += __shfl_xor(ss, 16);
        ss += __shfl_xor(ss, 32);
        const float rn = 1.0f / fmaxf(sqrtf(ss), 1e-12f);
#pragma unroll
        for (int ks = 0; ks < 8; ++ks) {
            bf16x8 a = {0, 0, 0, 0, 0, 0, 0, 0};
            if (c < Cn) {   // pass 2: reload (cache-hot), scale, convert
                float4 x0 = *(const float4*)(wr + ks * 32 + q * 8);
                float4 x1 = *(const float4*)(wr + ks * 32 + q * 8 + 4);
                a[0] = f2bf_rne(x0.x * rn); a[1] = f2bf_rne(x0.y * rn);
                a[2] = f2bf_rne(x0.z * rn); a[3] = f2bf_rne(x0.w * rn);
                a[4] = f2bf_rne(x1.x * rn); a[5] = f2bf_rne(x1.y * rn);
                a[6] = f2bf_rne(x1.z * rn); a[7] = f2bf_rne(x1.w * rn);
            }
            *(bf16x8*)(afrag_sh + (size_t)((wv * 8 + ks) * 64 + lane) * 8) = a;
        }
    }
    __syncthreads();

    float* pout = partial + (size_t)sl * Bn;
    const bf16x8* bsrc = (const bf16x8*)embF;   // chunk-indexed (16B units)
    const int t0 = wv * NTW;                    // this wave's 16 tiles of 32

    // B fragments for 32-tile t = 16-tiles (2t, 2t+1): coalesced 1KB/inst
    auto load_b = [&](bf16x8 (&bf)[2][8], int t) {
        const bf16x8* p = bsrc + ((size_t)(2 * t) * 512) + lane;
#pragma unroll
        for (int h = 0; h < 2; ++h)
#pragma unroll
            for (int ks = 0; ks < 8; ++ks) bf[h][ks] = p[h * 512 + ks * 64];
    };

    auto compute = [&](bf16x8 (&bf)[2][8], int t) {
        f32x4 acc[4][2];
#pragma unroll
        for (int ct = 0; ct < 4; ++ct)
#pragma unroll
            for (int h = 0; h < 2; ++h) acc[ct][h] = (f32x4){0.f, 0.f, 0.f, 0.f};
#pragma unroll
        for (int ks = 0; ks < 8; ++ks) {
            const short* ap = afrag_sh + (size_t)(ks * 64 + lane) * 8;
            bf16x8 w0 = *(const bf16x8*)(ap);            // ct stride = 4096 shorts
            bf16x8 w1 = *(const bf16x8*)(ap + 4096);
            bf16x8 w2 = *(const bf16x8*)(ap + 8192);
            bf16x8 w3 = *(const bf16x8*)(ap + 12288);
            // each A-frag read feeds TWO MFMAs (the two 16-col B halves)
            acc[0][0] = __builtin_amdgcn_mfma_f32_16x16x32_bf16(w0, bf[0][ks], acc[0][0], 0, 0, 0);
            acc[0][1] = __builtin_amdgcn_mfma_f32_16x16x32_bf16(w0, bf[1][ks], acc[0][1], 0, 0, 0);
            acc[1][0] = __builtin_amdgcn_mfma_f32_16x16x32_bf16(w1, bf[0][ks], acc[1][0], 0, 0, 0);
            acc[1][1] = __builtin_amdgcn_mfma_f32_16x16x32_bf16(w1, bf[1][ks], acc[1][1], 0, 0, 0);
            acc[2][0] = __builtin_amdgcn_mfma_f32_16x16x32_bf16(w2, bf[0][ks], acc[2][0], 0, 0, 0);
            acc[2][1] = __builtin_amdgcn_mfma_f32_16x16x32_bf16(w2, bf[1][ks], acc[2][1], 0, 0, 0);
            acc[3][0] = __builtin_amdgcn_mfma_f32_16x16x32_bf16(w3, bf[0][ks], acc[3][0], 0, 0, 0);
            acc[3][1] = __builtin_amdgcn_mfma_f32_16x16x32_bf16(w3, bf[1][ks], acc[3][1], 0, 0, 0);
        }
        // D layout: col=lane&15=sample, row=q*4+reg=class. d = 30*log2e*cos,
        // so exp(30*cos) = exp2(d). Per-half sums, 4 independent chains each.
        float sh[2];
#pragma unroll
        for (int h = 0; h < 2; ++h) {
            float s0 = 0.f, s1 = 0.f, s2 = 0.f, s3 = 0.f;
#pragma unroll
            for (int ct = 0; ct < 4; ++ct) {
                s0 += __builtin_amdgcn_exp2f(acc[ct][h][0]);
                s1 += __builtin_amdgcn_exp2f(acc[ct][h][1]);
                s2 += __builtin_amdgcn_exp2f(acc[ct][h][2]);
                s3 += __builtin_amdgcn_exp2f(acc[ct][h][3]);
            }
            float s = (s0 + s1) + (s2 + s3);
            s += __shfl_xor(s, 16);      // fold q bits: every lane gets
            s += __shfl_xor(s, 32);      // the full class-sum for its cr
            sh[h] = s;
        }
        // one coalesced 128B store: lanes 0-15 -> half 0, lanes 16-31 -> half 1
        if (lane < 32) pout[t * 32 + lane] = (lane < 16) ? sh[0] : sh[1];
    };

    bf16x8 b0[2][8], b1[2][8];
    load_b(b0, t0);
    for (int i = 0; i < NTW; i += 2) {
        load_b(b1, t0 + i + 1);                          // prefetch next tile
        compute(b0, t0 + i);
        load_b(b0, (i + 2) < NTW ? (t0 + i + 2) : t0);   // overrun-clamped
        compute(b1, t0 + i + 1);
    }
}

// ---- kernel 3: fused rowsum + loss ----
// 128 blocks x 256 thr; block owns 16 samples; tid = chunk*16 + l.
__global__ __launch_bounds__(256) void k_finish(const float* __restrict__ partial,
                                                const float* __restrict__ numv,
                                                const float* __restrict__ etv,
                                                float* __restrict__ out) {
    __shared__ float red[16];
    const int l     = threadIdx.x & 15;          // sample within block
    const int chunk = threadIdx.x >> 4;          // 0..15
    const int b  = blockIdx.x * 16 + l;

    if (threadIdx.x < 16) red[threadIdx.x] = 0.0f;
    __syncthreads();

    float acc = 0.0f;
    for (int s = chunk; s < NSLICE; s += 16) acc += partial[(size_t)s * Bn + b];
    // wave holds 4 chunks x 16 samples: fold chunks in-wave first
    acc += __shfl_xor(acc, 16);
    acc += __shfl_xor(acc, 32);
    if ((threadIdx.x & 63) < 16) atomicAdd(&red[l], acc);
    __syncthreads();

    if (threadIdx.x < 16) {
        const int bb = blockIdx.x * 16 + threadIdx.x;
        const float num  = numv[bb];
        const float excl = red[threadIdx.x] - OOB_COLS - etv[bb];  // drop pad + target
        float term = num - logf(__expf(num) + excl + EPS_F);
#pragma unroll
        for (int o = 1; o < 16; o <<= 1) term += __shfl_xor(term, o);
        if (threadIdx.x == 0) atomicAdd(out, -term / (float)Bn);
    }
}

extern "C" void kernel_launch(void* const* d_in, const int* in_sizes, int n_in,
                              void* d_out, int out_size, void* d_ws, size_t ws_size,
                              hipStream_t stream) {
    const float* emb = (const float*)d_in[0];   // 2048*256
    const float* W   = (const float*)d_in[1];   // 100000*256
    const int*   tgt = (const int*)d_in[2];     // 2048
    float* out = (float*)d_out;

    char* ws = (char*)d_ws;
    short* embF    = (short*)ws;                             // 1 MB (fragment order)
    float* partial = (float*)(ws + (1 << 20));               // 1564*2048*4 = 12.8 MB
    float* numv    = partial + (size_t)NSLICE * Bn;          // 8 KB
    float* etv     = numv + Bn;                              // 8 KB

    hipMemsetAsync(out, 0, sizeof(float), stream);
    k_prep<<<768, 256, 0, stream>>>(W, emb, tgt, embF, numv, etv);
    k_main<<<NSLICE, 256, 0, stream>>>(W, embF, partial);
    k_finish<<<128, 256, 0, stream>>>(partial, numv, etv, out);
}